// Round 12
// baseline (602.692 us; speedup 1.0000x reference)
//
#include <hip/hip_runtime.h>
#include <cstdint>
#include <cstddef>

// ---------------------------------------------------------------------------
// GCN 3-layer + FC head. Round 12: spmv 4-nodes/wave (1KB per gather instr),
// scaled-representation (store only hs=dis*h; h@W1 = idis*(hs@W1)) halves
// mfma writes. Split accumulators, idis from cfill.
// ---------------------------------------------------------------------------

typedef __attribute__((ext_vector_type(4))) float f32x4;
typedef __attribute__((ext_vector_type(8))) short bf16x8;
typedef unsigned short u16;

#define G_CHUNKS 256

__device__ __forceinline__ float bf2f(unsigned int u) {
  union { unsigned int i; float f; } v;
  v.i = u << 16;
  return v.f;
}
__device__ __forceinline__ u16 f2bf(float f) {
  union { float f; unsigned int i; } v;
  v.f = f;
  unsigned int i = v.i;
  return (u16)((i + 0x7FFFu + ((i >> 16) & 1u)) >> 16);  // RNE
}

// ---------------- CSR build: counting sort by dst bucket ----------------

__global__ __launch_bounds__(256) void k_hist(const int* __restrict__ ei,
                                              int* __restrict__ ghist,
                                              int E, int B, int chunk) {
  __shared__ int h[512];
  for (int t = threadIdx.x; t < B; t += 256) h[t] = 0;
  __syncthreads();
  const int g = blockIdx.x;
  const int beg = g * chunk;
  const int end = min(beg + chunk, E);
  for (int e = beg + threadIdx.x; e < end; e += 256)
    atomicAdd(&h[ei[E + e] >> 8], 1);
  __syncthreads();
  for (int t = threadIdx.x; t < B; t += 256) ghist[(size_t)t * G_CHUNKS + g] = h[t];
}

__global__ __launch_bounds__(256) void k_hscan(int* __restrict__ ghist,
                                               int* __restrict__ btot) {
  __shared__ int sm[256];
  int* p = ghist + (size_t)blockIdx.x * G_CHUNKS;
  const int t = threadIdx.x;
  int v = p[t];
  sm[t] = v;
  __syncthreads();
  for (int off = 1; off < 256; off <<= 1) {
    int u = (t >= off) ? sm[t - off] : 0;
    __syncthreads();
    sm[t] += u;
    __syncthreads();
  }
  p[t] = sm[t] - v;                     // exclusive
  if (t == 255) btot[blockIdx.x] = sm[255];
}

__global__ __launch_bounds__(512) void k_bscan(const int* __restrict__ btot,
                                               int* __restrict__ boff, int B,
                                               int* __restrict__ rowptr, int n,
                                               int E, int tot) {
  __shared__ int sm[512];
  const int t = threadIdx.x;
  int v = (t < B) ? btot[t] : 0;
  sm[t] = v;
  __syncthreads();
  for (int off = 1; off < 512; off <<= 1) {
    int u = (t >= off) ? sm[t - off] : 0;
    __syncthreads();
    sm[t] += u;
    __syncthreads();
  }
  if (t < B) boff[t] = sm[t] - v;       // exclusive
  if (t == 0) {
    boff[B] = E;
    rowptr[n] = tot;
  }
}

__global__ __launch_bounds__(256) void k_scatter(const int* __restrict__ ei,
                                                 const int* __restrict__ ghist,
                                                 const int* __restrict__ boff,
                                                 unsigned int* __restrict__ ebuf,
                                                 int E, int B, int chunk) {
  __shared__ int off[512];
  const int g = blockIdx.x;
  for (int t = threadIdx.x; t < B; t += 256)
    off[t] = boff[t] + ghist[(size_t)t * G_CHUNKS + g];
  __syncthreads();
  const int beg = g * chunk;
  const int end = min(beg + chunk, E);
  for (int e = beg + threadIdx.x; e < end; e += 256) {
    int s = ei[e];
    int d = ei[E + e];
    int pos = atomicAdd(&off[d >> 8], 1);
    ebuf[pos] = ((unsigned int)s << 8) | (unsigned int)(d & 255);
  }
}

__global__ __launch_bounds__(256) void k_cfill(const unsigned int* __restrict__ ebuf,
                                               const int* __restrict__ boff,
                                               int* __restrict__ rowptr,
                                               int* __restrict__ col,
                                               float* __restrict__ dis,
                                               float* __restrict__ idis, int n) {
  __shared__ int cnt[256];
  __shared__ int fl[256];
  const int b = blockIdx.x;
  const int t = threadIdx.x;
  const int beg = boff[b];
  const int end = boff[b + 1];
  const int node0 = b << 8;
  const int nn = min(256, n - node0);
  cnt[t] = 0;
  __syncthreads();
  for (int e = beg + t; e < end; e += 256)
    atomicAdd(&cnt[ebuf[e] & 255u], 1);
  __syncthreads();
  int v = cnt[t];
  __shared__ int sm[256];
  sm[t] = v;
  __syncthreads();
  for (int off = 1; off < 256; off <<= 1) {
    int u = (t >= off) ? sm[t - off] : 0;
    __syncthreads();
    sm[t] += u;
    __syncthreads();
  }
  if (t < nn) {
    int excl = sm[t] - v;
    int rbase = beg + node0 + t + excl;   // earlier buckets' edges + self-loops
    int i = node0 + t;
    rowptr[i] = rbase;
    col[rbase] = i;                        // self-loop first
    fl[t] = rbase + 1;
    float dv = (float)(v + 1);
    dis[i] = rsqrtf(dv);
    idis[i] = sqrtf(dv);
  }
  __syncthreads();
  for (int e = beg + t; e < end; e += 256) {
    unsigned int pk = ebuf[e];
    int pos = atomicAdd(&fl[pk & 255u], 1);
    col[pos] = (int)(pk >> 8);
  }
}

// ---------------- dtype prep ----------------

// X fp32 -> Xs (bf16, pre-scaled by dis[row]); 8 elems/thread.
__global__ __launch_bounds__(256) void k_cvt(const float* __restrict__ src,
                                             const float* __restrict__ dis,
                                             u16* __restrict__ dsts, int total8) {
  int i = blockIdx.x * 256 + threadIdx.x;
  if (i >= total8) return;
  size_t b = (size_t)i * 8;
  float ds = dis[i >> 4];               // 16 threads x 8 elems = one 128-row
  float4 a0 = *(const float4*)(src + b);
  float4 a1 = *(const float4*)(src + b + 4);
  u16 os[8] = {f2bf(a0.x * ds), f2bf(a0.y * ds), f2bf(a0.z * ds), f2bf(a0.w * ds),
               f2bf(a1.x * ds), f2bf(a1.y * ds), f2bf(a1.z * ds), f2bf(a1.w * ds)};
  *(ulonglong2*)(dsts + b) = *(ulonglong2*)os;
}

// blocks 0..767: WT[z][nr][k] = bf16(W_z[k][nr])
// blocks 768..770: bias sums; blocks 771..834: fcT[nr][k] = bf16(fcw[k][nr])
__global__ __launch_bounds__(128) void k_prep(const float* __restrict__ w0,
                                              const float* __restrict__ w1,
                                              const float* __restrict__ w2,
                                              const float* __restrict__ w3,
                                              const float* __restrict__ w4,
                                              const float* __restrict__ w5,
                                              const float* __restrict__ g1,
                                              const float* __restrict__ l1,
                                              const float* __restrict__ g2,
                                              const float* __restrict__ l2,
                                              const float* __restrict__ g3,
                                              const float* __restrict__ l3,
                                              const float* __restrict__ fcw,
                                              u16* __restrict__ wt,
                                              float* __restrict__ bias,
                                              u16* __restrict__ fcT) {
  int bx = blockIdx.x;
  if (bx < 768) {
    int z = bx >> 7, nr = bx & 127, k = threadIdx.x;
    const float* Ws[6] = {w0, w1, w2, w3, w4, w5};
    wt[(size_t)z * 16384 + nr * 128 + k] = f2bf(Ws[z][k * 128 + nr]);
  } else if (bx < 771) {
    int t = (bx - 768) * 128 + threadIdx.x;
    if (t < 384) {
      const float* gs[3] = {g1, g2, g3};
      const float* ls[3] = {l1, l2, l3};
      bias[t] = gs[t >> 7][t & 127] + ls[t >> 7][t & 127];
    }
  } else {
    int nr = bx - 771;                 // 0..63
    int k = threadIdx.x;
    fcT[nr * 128 + k] = f2bf(fcw[k * 64 + nr]);
  }
}

// ---------------------------------------------------------------------------
// SXb[i] = bf16( dis[i] * sum_j Xs[col[j], :] )   (Xs pre-scaled by dis)
// 4 nodes per wave: 16 lanes/node, uint4 (8 bf16)/lane -> one load instr
// gathers 1KB across four rows. 8-edge unroll per node.
// ---------------------------------------------------------------------------
__global__ __launch_bounds__(256, 8) void k_spmv_bf(const int* __restrict__ rowptr,
                                                    const int* __restrict__ col,
                                                    const float* __restrict__ dis,
                                                    const u16* __restrict__ Xs,
                                                    u16* __restrict__ SXb, int n) {
  const int tid = threadIdx.x;
  const int sub = tid & 15;             // lane within node (8 bf16 each)
  const int i = blockIdx.x * 16 + (tid >> 4);
  if (i >= n) return;
  int j = rowptr[i];
  const int end = rowptr[i + 1];
  float a0 = 0.f, a1 = 0.f, a2 = 0.f, a3 = 0.f;
  float a4 = 0.f, a5 = 0.f, a6 = 0.f, a7 = 0.f;

#define ROWQ(c) (*(const uint4*)(Xs + (size_t)(c) * 128 + sub * 8))
#define ACC(q)  do { uint4 _q = (q); \
                     a0 += bf2f(_q.x & 0xffffu); a1 += bf2f(_q.x >> 16); \
                     a2 += bf2f(_q.y & 0xffffu); a3 += bf2f(_q.y >> 16); \
                     a4 += bf2f(_q.z & 0xffffu); a5 += bf2f(_q.z >> 16); \
                     a6 += bf2f(_q.w & 0xffffu); a7 += bf2f(_q.w >> 16); } while (0)

  for (; (j & 3) && j < end; ++j) ACC(ROWQ(col[j]));
  for (; j + 7 < end; j += 8) {
    int4 c0 = *(const int4*)(col + j);
    int4 c1 = *(const int4*)(col + j + 4);
    uint4 q0 = ROWQ(c0.x), q1 = ROWQ(c0.y), q2 = ROWQ(c0.z), q3 = ROWQ(c0.w);
    uint4 q4 = ROWQ(c1.x), q5 = ROWQ(c1.y), q6 = ROWQ(c1.z), q7 = ROWQ(c1.w);
    ACC(q0); ACC(q1); ACC(q2); ACC(q3);
    ACC(q4); ACC(q5); ACC(q6); ACC(q7);
  }
  if (j + 3 < end) {
    int4 c0 = *(const int4*)(col + j);
    uint4 q0 = ROWQ(c0.x), q1 = ROWQ(c0.y), q2 = ROWQ(c0.z), q3 = ROWQ(c0.w);
    ACC(q0); ACC(q1); ACC(q2); ACC(q3);
    j += 4;
  }
  for (; j < end; ++j) ACC(ROWQ(col[j]));
#undef ROWQ
#undef ACC

  const float di = dis[i];
  uint4 o;
  o.x = (unsigned int)f2bf(a0 * di) | ((unsigned int)f2bf(a1 * di) << 16);
  o.y = (unsigned int)f2bf(a2 * di) | ((unsigned int)f2bf(a3 * di) << 16);
  o.z = (unsigned int)f2bf(a4 * di) | ((unsigned int)f2bf(a5 * di) << 16);
  o.w = (unsigned int)f2bf(a6 * di) | ((unsigned int)f2bf(a7 * di) << 16);
  *(uint4*)(SXb + (size_t)i * 128 + sub * 8) = o;
}

// ---------------------------------------------------------------------------
// MFMA fused layer, 4-way COLUMN-SPLIT, scaled representation:
//   v = lrelu( A0@W0 + idis[row]*(A1s@W1) + bias )
// A0 = SX (bf16), A1s = dis-scaled prev features hs. Split accumulators.
// outs: bf16 dis[row]*v (hs for next layer / FC);  outf: fp32 v (final h).
// grid (gM, 4); per wave 32 rows x 32 cols, accA/accB [2][2].
// gfx950 16x16x32 mapping: A/B lane l -> row/col l&15, k (l>>4)*8+e;
//                          D lane l -> col l&15, row (l>>4)*4+e.
// NOT in-place safe -> caller rotates buffers.
// ---------------------------------------------------------------------------
__global__ __launch_bounds__(256, 8) void k_mfma(const u16* __restrict__ A0,
                                                 const u16* __restrict__ A1s,
                                                 const u16* __restrict__ W0T,
                                                 const u16* __restrict__ W1T,
                                                 const float* __restrict__ bias,
                                                 const float* __restrict__ dis,
                                                 const float* __restrict__ idis,
                                                 u16* __restrict__ outs,
                                                 float* __restrict__ outf, int M) {
  const int lane = threadIdx.x & 63;
  const int wv = threadIdx.x >> 6;
  const int row0 = blockIdx.x * 128 + wv * 32;
  const int c0off = blockIdx.y * 32;     // column slice
  const int r = lane & 15;
  const int kg = lane >> 4;

  f32x4 accA[2][2], accB[2][2];
#pragma unroll
  for (int a = 0; a < 2; ++a)
#pragma unroll
    for (int j = 0; j < 2; ++j) {
      accA[a][j] = (f32x4){0.f, 0.f, 0.f, 0.f};
      accB[a][j] = (f32x4){0.f, 0.f, 0.f, 0.f};
    }

  const int ra0 = min(row0 + r, M - 1);
  const int ra1 = min(row0 + 16 + r, M - 1);

  // A0 @ W0 -> accA
#pragma unroll
  for (int kk = 0; kk < 4; ++kk) {
    const int k0 = kk * 32 + kg * 8;
    bf16x8 a0 = *(const bf16x8*)(A0 + (size_t)ra0 * 128 + k0);
    bf16x8 a1 = *(const bf16x8*)(A0 + (size_t)ra1 * 128 + k0);
#pragma unroll
    for (int j = 0; j < 2; ++j) {
      bf16x8 b = *(const bf16x8*)(W0T + (size_t)(c0off + j * 16 + r) * 128 + k0);
      accA[0][j] = __builtin_amdgcn_mfma_f32_16x16x32_bf16(a0, b, accA[0][j], 0, 0, 0);
      accA[1][j] = __builtin_amdgcn_mfma_f32_16x16x32_bf16(a1, b, accA[1][j], 0, 0, 0);
    }
  }
  // A1s @ W1 -> accB
#pragma unroll
  for (int kk = 0; kk < 4; ++kk) {
    const int k0 = kk * 32 + kg * 8;
    bf16x8 a0 = *(const bf16x8*)(A1s + (size_t)ra0 * 128 + k0);
    bf16x8 a1 = *(const bf16x8*)(A1s + (size_t)ra1 * 128 + k0);
#pragma unroll
    for (int j = 0; j < 2; ++j) {
      bf16x8 b = *(const bf16x8*)(W1T + (size_t)(c0off + j * 16 + r) * 128 + k0);
      accB[0][j] = __builtin_amdgcn_mfma_f32_16x16x32_bf16(a0, b, accB[0][j], 0, 0, 0);
      accB[1][j] = __builtin_amdgcn_mfma_f32_16x16x32_bf16(a1, b, accB[1][j], 0, 0, 0);
    }
  }

#pragma unroll
  for (int rf = 0; rf < 2; ++rf)
#pragma unroll
    for (int e = 0; e < 4; ++e) {
      const int row = row0 + rf * 16 + kg * 4 + e;
      if (row >= M) continue;
      const float ids = idis[row];
      const float ds = dis[row];
#pragma unroll
      for (int j = 0; j < 2; ++j) {
        const int c = c0off + j * 16 + r;
        float v = accA[rf][j][e] + ids * accB[rf][j][e] + bias[c];
        v = (v > 0.f) ? v : 0.01f * v;
        if (outf) outf[(size_t)row * 128 + c] = v;
        if (outs) outs[(size_t)row * 128 + c] = f2bf(v * ds);
      }
    }
}

// ---------------------------------------------------------------------------
// FC head via MFMA, scaled input: y = idis[row]*(hs3@fcT) + fcb.
// hs3 bf16 [M,128] (dis-scaled h3), fcT bf16 [64][128]. hs3 may live in the
// y region (row-aligned): each wave reads its rows before storing them.
// ---------------------------------------------------------------------------
__global__ __launch_bounds__(256) void k_fc_mfma(const u16* __restrict__ hs3,
                                                 const u16* __restrict__ fcT,
                                                 const float* __restrict__ fcb,
                                                 const float* __restrict__ idis,
                                                 float* __restrict__ y, int M) {
  const int lane = threadIdx.x & 63;
  const int wv = threadIdx.x >> 6;
  const int row0 = blockIdx.x * 128 + wv * 32;
  const int r = lane & 15;
  const int kg = lane >> 4;

  f32x4 acc[2][4];
#pragma unroll
  for (int a = 0; a < 2; ++a)
#pragma unroll
    for (int j = 0; j < 4; ++j) acc[a][j] = (f32x4){0.f, 0.f, 0.f, 0.f};

  const int ra0 = min(row0 + r, M - 1);
  const int ra1 = min(row0 + 16 + r, M - 1);

#pragma unroll
  for (int kk = 0; kk < 4; ++kk) {
    const int k0 = kk * 32 + kg * 8;
    bf16x8 a0 = *(const bf16x8*)(hs3 + (size_t)ra0 * 128 + k0);
    bf16x8 a1 = *(const bf16x8*)(hs3 + (size_t)ra1 * 128 + k0);
#pragma unroll
    for (int j = 0; j < 4; ++j) {
      bf16x8 b = *(const bf16x8*)(fcT + (size_t)(j * 16 + r) * 128 + k0);
      acc[0][j] = __builtin_amdgcn_mfma_f32_16x16x32_bf16(a0, b, acc[0][j], 0, 0, 0);
      acc[1][j] = __builtin_amdgcn_mfma_f32_16x16x32_bf16(a1, b, acc[1][j], 0, 0, 0);
    }
  }

#pragma unroll
  for (int rf = 0; rf < 2; ++rf)
#pragma unroll
    for (int e = 0; e < 4; ++e) {
      const int row = row0 + rf * 16 + kg * 4 + e;
      if (row >= M) continue;
      const float ids = idis[row];
#pragma unroll
      for (int j = 0; j < 4; ++j) {
        const int c = j * 16 + r;
        y[(size_t)row * 64 + c] = ids * acc[rf][j][e] + fcb[c];
      }
    }
}

// ---------------------------------------------------------------------------

extern "C" void kernel_launch(void* const* d_in, const int* in_sizes, int n_in,
                              void* d_out, int out_size, void* d_ws, size_t ws_size,
                              hipStream_t stream) {
  const float* X  = (const float*)d_in[0];
  const int* ei   = (const int*)d_in[1];
  const float* gw1 = (const float*)d_in[3];
  const float* gb1 = (const float*)d_in[4];
  const float* lw1 = (const float*)d_in[5];
  const float* lb1 = (const float*)d_in[6];
  const float* gw2 = (const float*)d_in[7];
  const float* gb2 = (const float*)d_in[8];
  const float* lw2 = (const float*)d_in[9];
  const float* lb2 = (const float*)d_in[10];
  const float* gw3 = (const float*)d_in[11];
  const float* gb3 = (const float*)d_in[12];
  const float* lw3 = (const float*)d_in[13];
  const float* lb3 = (const float*)d_in[14];
  const float* fcw = (const float*)d_in[15];
  const float* fcb = (const float*)d_in[16];

  const int n = in_sizes[0] / 128;
  const int E = in_sizes[1] / 2;
  const int tot = E + n;
  const int B = (n + 255) >> 8;        // buckets (<=512)
  const int chunk = (E + G_CHUNKS - 1) / G_CHUNKS;

  char* ws = (char*)d_ws;
  size_t off = 0;
  auto alloc = [&](size_t bytes) -> void* {
    void* p = ws + off;
    off = (off + bytes + 255) & ~(size_t)255;
    return p;
  };
  int* ghist   = (int*)alloc((size_t)B * G_CHUNKS * 4);
  int* btot    = (int*)alloc(512 * 4);
  int* boff    = (int*)alloc((size_t)(B + 1) * 4);
  int* rowptr  = (int*)alloc((size_t)(n + 1) * 4);
  float* dis   = (float*)alloc((size_t)n * 4);
  float* idis  = (float*)alloc((size_t)n * 4);
  int* col     = (int*)alloc((size_t)tot * 4);
  unsigned int* ebuf = (unsigned int*)alloc((size_t)E * 4);
  u16* Xs      = (u16*)alloc((size_t)n * 128 * 2);   // scaled features ping A
  u16* SXb     = (u16*)alloc((size_t)n * 128 * 2);
  u16* WT      = (u16*)alloc((size_t)6 * 16384 * 2);
  u16* fcT     = (u16*)alloc((size_t)64 * 128 * 2);
  float* bias  = (float*)alloc(384 * 4);          // total ~66 MB

  float* outh = (float*)d_out;                 // [n,128] final h fp32
  float* outy = outh + (size_t)n * 128;        // [n,64]  final y fp32
  u16* hb = (u16*)outy;  // scaled-feature ping B in y-region (row-aligned);
                         // overwritten row-by-row by k_fc_mfma at the end.

  const int gM = (n + 127) / 128;
  const int gW = (n + 15) / 16;        // 16 nodes per block (4 per wave)
  const int g8 = (n * 128 / 8 + 255) / 256;

  // ---- CSR build (counting sort) ----
  k_hist<<<G_CHUNKS, 256, 0, stream>>>(ei, ghist, E, B, chunk);
  k_hscan<<<B, 256, 0, stream>>>(ghist, btot);
  k_bscan<<<1, 512, 0, stream>>>(btot, boff, B, rowptr, n, E, tot);
  k_scatter<<<G_CHUNKS, 256, 0, stream>>>(ei, ghist, boff, ebuf, E, B, chunk);
  k_cfill<<<B, 256, 0, stream>>>(ebuf, boff, rowptr, col, dis, idis, n);

  // ---- dtype prep (k_cvt needs dis -> after cfill) ----
  k_cvt<<<g8, 256, 0, stream>>>(X, dis, Xs, n * 128 / 8);
  k_prep<<<835, 128, 0, stream>>>(gw1, lw1, gw2, lw2, gw3, lw3,
                                  gb1, lb1, gb2, lb2, gb3, lb3, fcw,
                                  WT, bias, fcT);

  // ---- layer 1: gather Xs; A1s=Xs -> hs1:hb ----
  k_spmv_bf<<<gW, 256, 0, stream>>>(rowptr, col, dis, Xs, SXb, n);
  k_mfma<<<dim3(gM, 4), 256, 0, stream>>>(SXb, Xs, WT, WT + 16384, bias,
                                          dis, idis, hb, nullptr, n);
  // ---- layer 2: gather hs1; A1s=hb -> hs2:Xs ----
  k_spmv_bf<<<gW, 256, 0, stream>>>(rowptr, col, dis, hb, SXb, n);
  k_mfma<<<dim3(gM, 4), 256, 0, stream>>>(SXb, hb, WT + 2 * 16384, WT + 3 * 16384,
                                          bias + 128, dis, idis, Xs, nullptr, n);
  // ---- layer 3: gather hs2; A1s=Xs -> h3 fp32:outh, hs3:hb ----
  k_spmv_bf<<<gW, 256, 0, stream>>>(rowptr, col, dis, Xs, SXb, n);
  k_mfma<<<dim3(gM, 4), 256, 0, stream>>>(SXb, Xs, WT + 4 * 16384, WT + 5 * 16384,
                                          bias + 256, dis, idis, hb, outh, n);
  // ---- FC head (reads hs3 in hb, y = idis*(hs3@fcT)+fcb, overwrites hb) ----
  k_fc_mfma<<<gM, 256, 0, stream>>>(hb, fcT, fcb, idis, outy, n);
}

// Round 13
// 446.636 us; speedup vs baseline: 1.3494x; 1.3494x over previous
//
#include <hip/hip_runtime.h>
#include <cstdint>
#include <cstddef>

// ---------------------------------------------------------------------------
// GCN 3-layer + FC head. Round 13: revert spmv to round-11 2-nodes/wave
// (4-nodes/wave doubled HBM traffic); keep round-12 scaled representation
// (store only hs=dis*h; h@W1 = idis*(hs@W1)).
// ---------------------------------------------------------------------------

typedef __attribute__((ext_vector_type(4))) float f32x4;
typedef __attribute__((ext_vector_type(8))) short bf16x8;
typedef unsigned short u16;

#define G_CHUNKS 256

__device__ __forceinline__ float bf2f(unsigned int u) {
  union { unsigned int i; float f; } v;
  v.i = u << 16;
  return v.f;
}
__device__ __forceinline__ u16 f2bf(float f) {
  union { float f; unsigned int i; } v;
  v.f = f;
  unsigned int i = v.i;
  return (u16)((i + 0x7FFFu + ((i >> 16) & 1u)) >> 16);  // RNE
}

// ---------------- CSR build: counting sort by dst bucket ----------------

__global__ __launch_bounds__(256) void k_hist(const int* __restrict__ ei,
                                              int* __restrict__ ghist,
                                              int E, int B, int chunk) {
  __shared__ int h[512];
  for (int t = threadIdx.x; t < B; t += 256) h[t] = 0;
  __syncthreads();
  const int g = blockIdx.x;
  const int beg = g * chunk;
  const int end = min(beg + chunk, E);
  for (int e = beg + threadIdx.x; e < end; e += 256)
    atomicAdd(&h[ei[E + e] >> 8], 1);
  __syncthreads();
  for (int t = threadIdx.x; t < B; t += 256) ghist[(size_t)t * G_CHUNKS + g] = h[t];
}

__global__ __launch_bounds__(256) void k_hscan(int* __restrict__ ghist,
                                               int* __restrict__ btot) {
  __shared__ int sm[256];
  int* p = ghist + (size_t)blockIdx.x * G_CHUNKS;
  const int t = threadIdx.x;
  int v = p[t];
  sm[t] = v;
  __syncthreads();
  for (int off = 1; off < 256; off <<= 1) {
    int u = (t >= off) ? sm[t - off] : 0;
    __syncthreads();
    sm[t] += u;
    __syncthreads();
  }
  p[t] = sm[t] - v;                     // exclusive
  if (t == 255) btot[blockIdx.x] = sm[255];
}

__global__ __launch_bounds__(512) void k_bscan(const int* __restrict__ btot,
                                               int* __restrict__ boff, int B,
                                               int* __restrict__ rowptr, int n,
                                               int E, int tot) {
  __shared__ int sm[512];
  const int t = threadIdx.x;
  int v = (t < B) ? btot[t] : 0;
  sm[t] = v;
  __syncthreads();
  for (int off = 1; off < 512; off <<= 1) {
    int u = (t >= off) ? sm[t - off] : 0;
    __syncthreads();
    sm[t] += u;
    __syncthreads();
  }
  if (t < B) boff[t] = sm[t] - v;       // exclusive
  if (t == 0) {
    boff[B] = E;
    rowptr[n] = tot;
  }
}

__global__ __launch_bounds__(256) void k_scatter(const int* __restrict__ ei,
                                                 const int* __restrict__ ghist,
                                                 const int* __restrict__ boff,
                                                 unsigned int* __restrict__ ebuf,
                                                 int E, int B, int chunk) {
  __shared__ int off[512];
  const int g = blockIdx.x;
  for (int t = threadIdx.x; t < B; t += 256)
    off[t] = boff[t] + ghist[(size_t)t * G_CHUNKS + g];
  __syncthreads();
  const int beg = g * chunk;
  const int end = min(beg + chunk, E);
  for (int e = beg + threadIdx.x; e < end; e += 256) {
    int s = ei[e];
    int d = ei[E + e];
    int pos = atomicAdd(&off[d >> 8], 1);
    ebuf[pos] = ((unsigned int)s << 8) | (unsigned int)(d & 255);
  }
}

__global__ __launch_bounds__(256) void k_cfill(const unsigned int* __restrict__ ebuf,
                                               const int* __restrict__ boff,
                                               int* __restrict__ rowptr,
                                               int* __restrict__ col,
                                               float* __restrict__ dis,
                                               float* __restrict__ idis, int n) {
  __shared__ int cnt[256];
  __shared__ int fl[256];
  const int b = blockIdx.x;
  const int t = threadIdx.x;
  const int beg = boff[b];
  const int end = boff[b + 1];
  const int node0 = b << 8;
  const int nn = min(256, n - node0);
  cnt[t] = 0;
  __syncthreads();
  for (int e = beg + t; e < end; e += 256)
    atomicAdd(&cnt[ebuf[e] & 255u], 1);
  __syncthreads();
  int v = cnt[t];
  __shared__ int sm[256];
  sm[t] = v;
  __syncthreads();
  for (int off = 1; off < 256; off <<= 1) {
    int u = (t >= off) ? sm[t - off] : 0;
    __syncthreads();
    sm[t] += u;
    __syncthreads();
  }
  if (t < nn) {
    int excl = sm[t] - v;
    int rbase = beg + node0 + t + excl;   // earlier buckets' edges + self-loops
    int i = node0 + t;
    rowptr[i] = rbase;
    col[rbase] = i;                        // self-loop first
    fl[t] = rbase + 1;
    float dv = (float)(v + 1);
    dis[i] = rsqrtf(dv);
    idis[i] = sqrtf(dv);
  }
  __syncthreads();
  for (int e = beg + t; e < end; e += 256) {
    unsigned int pk = ebuf[e];
    int pos = atomicAdd(&fl[pk & 255u], 1);
    col[pos] = (int)(pk >> 8);
  }
}

// ---------------- dtype prep ----------------

// X fp32 -> Xs (bf16, pre-scaled by dis[row]); 8 elems/thread.
__global__ __launch_bounds__(256) void k_cvt(const float* __restrict__ src,
                                             const float* __restrict__ dis,
                                             u16* __restrict__ dsts, int total8) {
  int i = blockIdx.x * 256 + threadIdx.x;
  if (i >= total8) return;
  size_t b = (size_t)i * 8;
  float ds = dis[i >> 4];               // 16 threads x 8 elems = one 128-row
  float4 a0 = *(const float4*)(src + b);
  float4 a1 = *(const float4*)(src + b + 4);
  u16 os[8] = {f2bf(a0.x * ds), f2bf(a0.y * ds), f2bf(a0.z * ds), f2bf(a0.w * ds),
               f2bf(a1.x * ds), f2bf(a1.y * ds), f2bf(a1.z * ds), f2bf(a1.w * ds)};
  *(ulonglong2*)(dsts + b) = *(ulonglong2*)os;
}

// blocks 0..767: WT[z][nr][k] = bf16(W_z[k][nr])
// blocks 768..770: bias sums; blocks 771..834: fcT[nr][k] = bf16(fcw[k][nr])
__global__ __launch_bounds__(128) void k_prep(const float* __restrict__ w0,
                                              const float* __restrict__ w1,
                                              const float* __restrict__ w2,
                                              const float* __restrict__ w3,
                                              const float* __restrict__ w4,
                                              const float* __restrict__ w5,
                                              const float* __restrict__ g1,
                                              const float* __restrict__ l1,
                                              const float* __restrict__ g2,
                                              const float* __restrict__ l2,
                                              const float* __restrict__ g3,
                                              const float* __restrict__ l3,
                                              const float* __restrict__ fcw,
                                              u16* __restrict__ wt,
                                              float* __restrict__ bias,
                                              u16* __restrict__ fcT) {
  int bx = blockIdx.x;
  if (bx < 768) {
    int z = bx >> 7, nr = bx & 127, k = threadIdx.x;
    const float* Ws[6] = {w0, w1, w2, w3, w4, w5};
    wt[(size_t)z * 16384 + nr * 128 + k] = f2bf(Ws[z][k * 128 + nr]);
  } else if (bx < 771) {
    int t = (bx - 768) * 128 + threadIdx.x;
    if (t < 384) {
      const float* gs[3] = {g1, g2, g3};
      const float* ls[3] = {l1, l2, l3};
      bias[t] = gs[t >> 7][t & 127] + ls[t >> 7][t & 127];
    }
  } else {
    int nr = bx - 771;                 // 0..63
    int k = threadIdx.x;
    fcT[nr * 128 + k] = f2bf(fcw[k * 64 + nr]);
  }
}

// ---------------------------------------------------------------------------
// SXb[i] = bf16( dis[i] * sum_j Xs[col[j], :] )   (Xs pre-scaled by dis)
// 2 nodes per wave: 32 lanes/node, uint2 (4 bf16)/lane -> one load instr
// gathers 512B across two rows (round-11 proven sweet spot). 8-edge unroll.
// ---------------------------------------------------------------------------
__global__ __launch_bounds__(256, 8) void k_spmv_bf(const int* __restrict__ rowptr,
                                                    const int* __restrict__ col,
                                                    const float* __restrict__ dis,
                                                    const u16* __restrict__ Xs,
                                                    u16* __restrict__ SXb, int n) {
  const int tid = threadIdx.x;
  const int half = (tid >> 5) & 1;      // which node within the wave
  const int sub = tid & 31;             // lane within node (4 bf16 each)
  const int i = blockIdx.x * 8 + (tid >> 6) * 2 + half;
  if (i >= n) return;
  int j = rowptr[i];
  const int end = rowptr[i + 1];
  float a0 = 0.f, a1 = 0.f, a2 = 0.f, a3 = 0.f;

#define ROWQ(c) (*(const uint2*)(Xs + (size_t)(c) * 128 + sub * 4))
#define ACC(q)  do { uint2 _q = (q); \
                     a0 += bf2f(_q.x & 0xffffu); a1 += bf2f(_q.x >> 16); \
                     a2 += bf2f(_q.y & 0xffffu); a3 += bf2f(_q.y >> 16); } while (0)

  for (; (j & 3) && j < end; ++j) ACC(ROWQ(col[j]));
  for (; j + 7 < end; j += 8) {
    int4 c0 = *(const int4*)(col + j);
    int4 c1 = *(const int4*)(col + j + 4);
    uint2 q0 = ROWQ(c0.x), q1 = ROWQ(c0.y), q2 = ROWQ(c0.z), q3 = ROWQ(c0.w);
    uint2 q4 = ROWQ(c1.x), q5 = ROWQ(c1.y), q6 = ROWQ(c1.z), q7 = ROWQ(c1.w);
    ACC(q0); ACC(q1); ACC(q2); ACC(q3);
    ACC(q4); ACC(q5); ACC(q6); ACC(q7);
  }
  if (j + 3 < end) {
    int4 c0 = *(const int4*)(col + j);
    uint2 q0 = ROWQ(c0.x), q1 = ROWQ(c0.y), q2 = ROWQ(c0.z), q3 = ROWQ(c0.w);
    ACC(q0); ACC(q1); ACC(q2); ACC(q3);
    j += 4;
  }
  for (; j < end; ++j) ACC(ROWQ(col[j]));
#undef ROWQ
#undef ACC

  const float di = dis[i];
  uint2 o;
  o.x = (unsigned int)f2bf(a0 * di) | ((unsigned int)f2bf(a1 * di) << 16);
  o.y = (unsigned int)f2bf(a2 * di) | ((unsigned int)f2bf(a3 * di) << 16);
  *(uint2*)(SXb + (size_t)i * 128 + sub * 4) = o;
}

// ---------------------------------------------------------------------------
// MFMA fused layer, 4-way COLUMN-SPLIT, scaled representation:
//   v = lrelu( A0@W0 + idis[row]*(A1s@W1) + bias )
// A0 = SX (bf16), A1s = dis-scaled prev features hs. Split accumulators.
// outs: bf16 dis[row]*v (hs for next layer / FC);  outf: fp32 v (final h).
// grid (gM, 4); per wave 32 rows x 32 cols, accA/accB [2][2].
// gfx950 16x16x32 mapping: A/B lane l -> row/col l&15, k (l>>4)*8+e;
//                          D lane l -> col l&15, row (l>>4)*4+e.
// NOT in-place safe -> caller rotates buffers.
// ---------------------------------------------------------------------------
__global__ __launch_bounds__(256, 8) void k_mfma(const u16* __restrict__ A0,
                                                 const u16* __restrict__ A1s,
                                                 const u16* __restrict__ W0T,
                                                 const u16* __restrict__ W1T,
                                                 const float* __restrict__ bias,
                                                 const float* __restrict__ dis,
                                                 const float* __restrict__ idis,
                                                 u16* __restrict__ outs,
                                                 float* __restrict__ outf, int M) {
  const int lane = threadIdx.x & 63;
  const int wv = threadIdx.x >> 6;
  const int row0 = blockIdx.x * 128 + wv * 32;
  const int c0off = blockIdx.y * 32;     // column slice
  const int r = lane & 15;
  const int kg = lane >> 4;

  f32x4 accA[2][2], accB[2][2];
#pragma unroll
  for (int a = 0; a < 2; ++a)
#pragma unroll
    for (int j = 0; j < 2; ++j) {
      accA[a][j] = (f32x4){0.f, 0.f, 0.f, 0.f};
      accB[a][j] = (f32x4){0.f, 0.f, 0.f, 0.f};
    }

  const int ra0 = min(row0 + r, M - 1);
  const int ra1 = min(row0 + 16 + r, M - 1);

  // A0 @ W0 -> accA
#pragma unroll
  for (int kk = 0; kk < 4; ++kk) {
    const int k0 = kk * 32 + kg * 8;
    bf16x8 a0 = *(const bf16x8*)(A0 + (size_t)ra0 * 128 + k0);
    bf16x8 a1 = *(const bf16x8*)(A0 + (size_t)ra1 * 128 + k0);
#pragma unroll
    for (int j = 0; j < 2; ++j) {
      bf16x8 b = *(const bf16x8*)(W0T + (size_t)(c0off + j * 16 + r) * 128 + k0);
      accA[0][j] = __builtin_amdgcn_mfma_f32_16x16x32_bf16(a0, b, accA[0][j], 0, 0, 0);
      accA[1][j] = __builtin_amdgcn_mfma_f32_16x16x32_bf16(a1, b, accA[1][j], 0, 0, 0);
    }
  }
  // A1s @ W1 -> accB
#pragma unroll
  for (int kk = 0; kk < 4; ++kk) {
    const int k0 = kk * 32 + kg * 8;
    bf16x8 a0 = *(const bf16x8*)(A1s + (size_t)ra0 * 128 + k0);
    bf16x8 a1 = *(const bf16x8*)(A1s + (size_t)ra1 * 128 + k0);
#pragma unroll
    for (int j = 0; j < 2; ++j) {
      bf16x8 b = *(const bf16x8*)(W1T + (size_t)(c0off + j * 16 + r) * 128 + k0);
      accB[0][j] = __builtin_amdgcn_mfma_f32_16x16x32_bf16(a0, b, accB[0][j], 0, 0, 0);
      accB[1][j] = __builtin_amdgcn_mfma_f32_16x16x32_bf16(a1, b, accB[1][j], 0, 0, 0);
    }
  }

#pragma unroll
  for (int rf = 0; rf < 2; ++rf)
#pragma unroll
    for (int e = 0; e < 4; ++e) {
      const int row = row0 + rf * 16 + kg * 4 + e;
      if (row >= M) continue;
      const float ids = idis[row];
      const float ds = dis[row];
#pragma unroll
      for (int j = 0; j < 2; ++j) {
        const int c = c0off + j * 16 + r;
        float v = accA[rf][j][e] + ids * accB[rf][j][e] + bias[c];
        v = (v > 0.f) ? v : 0.01f * v;
        if (outf) outf[(size_t)row * 128 + c] = v;
        if (outs) outs[(size_t)row * 128 + c] = f2bf(v * ds);
      }
    }
}

// ---------------------------------------------------------------------------
// FC head via MFMA, scaled input: y = idis[row]*(hs3@fcT) + fcb.
// hs3 bf16 [M,128] (dis-scaled h3), fcT bf16 [64][128]. hs3 may live in the
// y region (row-aligned): each wave reads its rows before storing them.
// ---------------------------------------------------------------------------
__global__ __launch_bounds__(256) void k_fc_mfma(const u16* __restrict__ hs3,
                                                 const u16* __restrict__ fcT,
                                                 const float* __restrict__ fcb,
                                                 const float* __restrict__ idis,
                                                 float* __restrict__ y, int M) {
  const int lane = threadIdx.x & 63;
  const int wv = threadIdx.x >> 6;
  const int row0 = blockIdx.x * 128 + wv * 32;
  const int r = lane & 15;
  const int kg = lane >> 4;

  f32x4 acc[2][4];
#pragma unroll
  for (int a = 0; a < 2; ++a)
#pragma unroll
    for (int j = 0; j < 4; ++j) acc[a][j] = (f32x4){0.f, 0.f, 0.f, 0.f};

  const int ra0 = min(row0 + r, M - 1);
  const int ra1 = min(row0 + 16 + r, M - 1);

#pragma unroll
  for (int kk = 0; kk < 4; ++kk) {
    const int k0 = kk * 32 + kg * 8;
    bf16x8 a0 = *(const bf16x8*)(hs3 + (size_t)ra0 * 128 + k0);
    bf16x8 a1 = *(const bf16x8*)(hs3 + (size_t)ra1 * 128 + k0);
#pragma unroll
    for (int j = 0; j < 4; ++j) {
      bf16x8 b = *(const bf16x8*)(fcT + (size_t)(j * 16 + r) * 128 + k0);
      acc[0][j] = __builtin_amdgcn_mfma_f32_16x16x32_bf16(a0, b, acc[0][j], 0, 0, 0);
      acc[1][j] = __builtin_amdgcn_mfma_f32_16x16x32_bf16(a1, b, acc[1][j], 0, 0, 0);
    }
  }

#pragma unroll
  for (int rf = 0; rf < 2; ++rf)
#pragma unroll
    for (int e = 0; e < 4; ++e) {
      const int row = row0 + rf * 16 + kg * 4 + e;
      if (row >= M) continue;
      const float ids = idis[row];
#pragma unroll
      for (int j = 0; j < 4; ++j) {
        const int c = j * 16 + r;
        y[(size_t)row * 64 + c] = ids * acc[rf][j][e] + fcb[c];
      }
    }
}

// ---------------------------------------------------------------------------

extern "C" void kernel_launch(void* const* d_in, const int* in_sizes, int n_in,
                              void* d_out, int out_size, void* d_ws, size_t ws_size,
                              hipStream_t stream) {
  const float* X  = (const float*)d_in[0];
  const int* ei   = (const int*)d_in[1];
  const float* gw1 = (const float*)d_in[3];
  const float* gb1 = (const float*)d_in[4];
  const float* lw1 = (const float*)d_in[5];
  const float* lb1 = (const float*)d_in[6];
  const float* gw2 = (const float*)d_in[7];
  const float* gb2 = (const float*)d_in[8];
  const float* lw2 = (const float*)d_in[9];
  const float* lb2 = (const float*)d_in[10];
  const float* gw3 = (const float*)d_in[11];
  const float* gb3 = (const float*)d_in[12];
  const float* lw3 = (const float*)d_in[13];
  const float* lb3 = (const float*)d_in[14];
  const float* fcw = (const float*)d_in[15];
  const float* fcb = (const float*)d_in[16];

  const int n = in_sizes[0] / 128;
  const int E = in_sizes[1] / 2;
  const int tot = E + n;
  const int B = (n + 255) >> 8;        // buckets (<=512)
  const int chunk = (E + G_CHUNKS - 1) / G_CHUNKS;

  char* ws = (char*)d_ws;
  size_t off = 0;
  auto alloc = [&](size_t bytes) -> void* {
    void* p = ws + off;
    off = (off + bytes + 255) & ~(size_t)255;
    return p;
  };
  int* ghist   = (int*)alloc((size_t)B * G_CHUNKS * 4);
  int* btot    = (int*)alloc(512 * 4);
  int* boff    = (int*)alloc((size_t)(B + 1) * 4);
  int* rowptr  = (int*)alloc((size_t)(n + 1) * 4);
  float* dis   = (float*)alloc((size_t)n * 4);
  float* idis  = (float*)alloc((size_t)n * 4);
  int* col     = (int*)alloc((size_t)tot * 4);
  unsigned int* ebuf = (unsigned int*)alloc((size_t)E * 4);
  u16* Xs      = (u16*)alloc((size_t)n * 128 * 2);   // scaled features ping A
  u16* SXb     = (u16*)alloc((size_t)n * 128 * 2);
  u16* WT      = (u16*)alloc((size_t)6 * 16384 * 2);
  u16* fcT     = (u16*)alloc((size_t)64 * 128 * 2);
  float* bias  = (float*)alloc(384 * 4);          // total ~66 MB

  float* outh = (float*)d_out;                 // [n,128] final h fp32
  float* outy = outh + (size_t)n * 128;        // [n,64]  final y fp32
  u16* hb = (u16*)outy;  // scaled-feature ping B in y-region (row-aligned);
                         // overwritten row-by-row by k_fc_mfma at the end.

  const int gM = (n + 127) / 128;
  const int gW = (n + 7) / 8;          // 8 nodes per block (2 per wave)
  const int g8 = (n * 128 / 8 + 255) / 256;

  // ---- CSR build (counting sort) ----
  k_hist<<<G_CHUNKS, 256, 0, stream>>>(ei, ghist, E, B, chunk);
  k_hscan<<<B, 256, 0, stream>>>(ghist, btot);
  k_bscan<<<1, 512, 0, stream>>>(btot, boff, B, rowptr, n, E, tot);
  k_scatter<<<G_CHUNKS, 256, 0, stream>>>(ei, ghist, boff, ebuf, E, B, chunk);
  k_cfill<<<B, 256, 0, stream>>>(ebuf, boff, rowptr, col, dis, idis, n);

  // ---- dtype prep (k_cvt needs dis -> after cfill) ----
  k_cvt<<<g8, 256, 0, stream>>>(X, dis, Xs, n * 128 / 8);
  k_prep<<<835, 128, 0, stream>>>(gw1, lw1, gw2, lw2, gw3, lw3,
                                  gb1, lb1, gb2, lb2, gb3, lb3, fcw,
                                  WT, bias, fcT);

  // ---- layer 1: gather Xs; A1s=Xs -> hs1:hb ----
  k_spmv_bf<<<gW, 256, 0, stream>>>(rowptr, col, dis, Xs, SXb, n);
  k_mfma<<<dim3(gM, 4), 256, 0, stream>>>(SXb, Xs, WT, WT + 16384, bias,
                                          dis, idis, hb, nullptr, n);
  // ---- layer 2: gather hs1; A1s=hb -> hs2:Xs ----
  k_spmv_bf<<<gW, 256, 0, stream>>>(rowptr, col, dis, hb, SXb, n);
  k_mfma<<<dim3(gM, 4), 256, 0, stream>>>(SXb, hb, WT + 2 * 16384, WT + 3 * 16384,
                                          bias + 128, dis, idis, Xs, nullptr, n);
  // ---- layer 3: gather hs2; A1s=Xs -> h3 fp32:outh, hs3:hb ----
  k_spmv_bf<<<gW, 256, 0, stream>>>(rowptr, col, dis, Xs, SXb, n);
  k_mfma<<<dim3(gM, 4), 256, 0, stream>>>(SXb, Xs, WT + 4 * 16384, WT + 5 * 16384,
                                          bias + 256, dis, idis, hb, outh, n);
  // ---- FC head (reads hs3 in hb, y = idis*(hs3@fcT)+fcb, overwrites hb) ----
  k_fc_mfma<<<gM, 256, 0, stream>>>(hb, fcT, fcb, idis, outy, n);
}

// Round 14
// 436.947 us; speedup vs baseline: 1.3793x; 1.0222x over previous
//
#include <hip/hip_runtime.h>
#include <cstdint>
#include <cstddef>

// ---------------------------------------------------------------------------
// GCN 3-layer + FC head. Round 14: XCD-aware swizzle on k_mfma's grid so the
// 4 column-slices of a row-block run on the SAME XCD (A-panel L2 reuse;
// fixes the 117MB re-fetch seen in round 13). Rest identical to round 13.
// ---------------------------------------------------------------------------

typedef __attribute__((ext_vector_type(4))) float f32x4;
typedef __attribute__((ext_vector_type(8))) short bf16x8;
typedef unsigned short u16;

#define G_CHUNKS 256

__device__ __forceinline__ float bf2f(unsigned int u) {
  union { unsigned int i; float f; } v;
  v.i = u << 16;
  return v.f;
}
__device__ __forceinline__ u16 f2bf(float f) {
  union { float f; unsigned int i; } v;
  v.f = f;
  unsigned int i = v.i;
  return (u16)((i + 0x7FFFu + ((i >> 16) & 1u)) >> 16);  // RNE
}

// ---------------- CSR build: counting sort by dst bucket ----------------

__global__ __launch_bounds__(256) void k_hist(const int* __restrict__ ei,
                                              int* __restrict__ ghist,
                                              int E, int B, int chunk) {
  __shared__ int h[512];
  for (int t = threadIdx.x; t < B; t += 256) h[t] = 0;
  __syncthreads();
  const int g = blockIdx.x;
  const int beg = g * chunk;
  const int end = min(beg + chunk, E);
  for (int e = beg + threadIdx.x; e < end; e += 256)
    atomicAdd(&h[ei[E + e] >> 8], 1);
  __syncthreads();
  for (int t = threadIdx.x; t < B; t += 256) ghist[(size_t)t * G_CHUNKS + g] = h[t];
}

__global__ __launch_bounds__(256) void k_hscan(int* __restrict__ ghist,
                                               int* __restrict__ btot) {
  __shared__ int sm[256];
  int* p = ghist + (size_t)blockIdx.x * G_CHUNKS;
  const int t = threadIdx.x;
  int v = p[t];
  sm[t] = v;
  __syncthreads();
  for (int off = 1; off < 256; off <<= 1) {
    int u = (t >= off) ? sm[t - off] : 0;
    __syncthreads();
    sm[t] += u;
    __syncthreads();
  }
  p[t] = sm[t] - v;                     // exclusive
  if (t == 255) btot[blockIdx.x] = sm[255];
}

__global__ __launch_bounds__(512) void k_bscan(const int* __restrict__ btot,
                                               int* __restrict__ boff, int B,
                                               int* __restrict__ rowptr, int n,
                                               int E, int tot) {
  __shared__ int sm[512];
  const int t = threadIdx.x;
  int v = (t < B) ? btot[t] : 0;
  sm[t] = v;
  __syncthreads();
  for (int off = 1; off < 512; off <<= 1) {
    int u = (t >= off) ? sm[t - off] : 0;
    __syncthreads();
    sm[t] += u;
    __syncthreads();
  }
  if (t < B) boff[t] = sm[t] - v;       // exclusive
  if (t == 0) {
    boff[B] = E;
    rowptr[n] = tot;
  }
}

__global__ __launch_bounds__(256) void k_scatter(const int* __restrict__ ei,
                                                 const int* __restrict__ ghist,
                                                 const int* __restrict__ boff,
                                                 unsigned int* __restrict__ ebuf,
                                                 int E, int B, int chunk) {
  __shared__ int off[512];
  const int g = blockIdx.x;
  for (int t = threadIdx.x; t < B; t += 256)
    off[t] = boff[t] + ghist[(size_t)t * G_CHUNKS + g];
  __syncthreads();
  const int beg = g * chunk;
  const int end = min(beg + chunk, E);
  for (int e = beg + threadIdx.x; e < end; e += 256) {
    int s = ei[e];
    int d = ei[E + e];
    int pos = atomicAdd(&off[d >> 8], 1);
    ebuf[pos] = ((unsigned int)s << 8) | (unsigned int)(d & 255);
  }
}

__global__ __launch_bounds__(256) void k_cfill(const unsigned int* __restrict__ ebuf,
                                               const int* __restrict__ boff,
                                               int* __restrict__ rowptr,
                                               int* __restrict__ col,
                                               float* __restrict__ dis,
                                               float* __restrict__ idis, int n) {
  __shared__ int cnt[256];
  __shared__ int fl[256];
  const int b = blockIdx.x;
  const int t = threadIdx.x;
  const int beg = boff[b];
  const int end = boff[b + 1];
  const int node0 = b << 8;
  const int nn = min(256, n - node0);
  cnt[t] = 0;
  __syncthreads();
  for (int e = beg + t; e < end; e += 256)
    atomicAdd(&cnt[ebuf[e] & 255u], 1);
  __syncthreads();
  int v = cnt[t];
  __shared__ int sm[256];
  sm[t] = v;
  __syncthreads();
  for (int off = 1; off < 256; off <<= 1) {
    int u = (t >= off) ? sm[t - off] : 0;
    __syncthreads();
    sm[t] += u;
    __syncthreads();
  }
  if (t < nn) {
    int excl = sm[t] - v;
    int rbase = beg + node0 + t + excl;   // earlier buckets' edges + self-loops
    int i = node0 + t;
    rowptr[i] = rbase;
    col[rbase] = i;                        // self-loop first
    fl[t] = rbase + 1;
    float dv = (float)(v + 1);
    dis[i] = rsqrtf(dv);
    idis[i] = sqrtf(dv);
  }
  __syncthreads();
  for (int e = beg + t; e < end; e += 256) {
    unsigned int pk = ebuf[e];
    int pos = atomicAdd(&fl[pk & 255u], 1);
    col[pos] = (int)(pk >> 8);
  }
}

// ---------------- dtype prep ----------------

// X fp32 -> Xs (bf16, pre-scaled by dis[row]); 8 elems/thread.
__global__ __launch_bounds__(256) void k_cvt(const float* __restrict__ src,
                                             const float* __restrict__ dis,
                                             u16* __restrict__ dsts, int total8) {
  int i = blockIdx.x * 256 + threadIdx.x;
  if (i >= total8) return;
  size_t b = (size_t)i * 8;
  float ds = dis[i >> 4];               // 16 threads x 8 elems = one 128-row
  float4 a0 = *(const float4*)(src + b);
  float4 a1 = *(const float4*)(src + b + 4);
  u16 os[8] = {f2bf(a0.x * ds), f2bf(a0.y * ds), f2bf(a0.z * ds), f2bf(a0.w * ds),
               f2bf(a1.x * ds), f2bf(a1.y * ds), f2bf(a1.z * ds), f2bf(a1.w * ds)};
  *(ulonglong2*)(dsts + b) = *(ulonglong2*)os;
}

// blocks 0..767: WT[z][nr][k] = bf16(W_z[k][nr])
// blocks 768..770: bias sums; blocks 771..834: fcT[nr][k] = bf16(fcw[k][nr])
__global__ __launch_bounds__(128) void k_prep(const float* __restrict__ w0,
                                              const float* __restrict__ w1,
                                              const float* __restrict__ w2,
                                              const float* __restrict__ w3,
                                              const float* __restrict__ w4,
                                              const float* __restrict__ w5,
                                              const float* __restrict__ g1,
                                              const float* __restrict__ l1,
                                              const float* __restrict__ g2,
                                              const float* __restrict__ l2,
                                              const float* __restrict__ g3,
                                              const float* __restrict__ l3,
                                              const float* __restrict__ fcw,
                                              u16* __restrict__ wt,
                                              float* __restrict__ bias,
                                              u16* __restrict__ fcT) {
  int bx = blockIdx.x;
  if (bx < 768) {
    int z = bx >> 7, nr = bx & 127, k = threadIdx.x;
    const float* Ws[6] = {w0, w1, w2, w3, w4, w5};
    wt[(size_t)z * 16384 + nr * 128 + k] = f2bf(Ws[z][k * 128 + nr]);
  } else if (bx < 771) {
    int t = (bx - 768) * 128 + threadIdx.x;
    if (t < 384) {
      const float* gs[3] = {g1, g2, g3};
      const float* ls[3] = {l1, l2, l3};
      bias[t] = gs[t >> 7][t & 127] + ls[t >> 7][t & 127];
    }
  } else {
    int nr = bx - 771;                 // 0..63
    int k = threadIdx.x;
    fcT[nr * 128 + k] = f2bf(fcw[k * 64 + nr]);
  }
}

// ---------------------------------------------------------------------------
// SXb[i] = bf16( dis[i] * sum_j Xs[col[j], :] )   (Xs pre-scaled by dis)
// 2 nodes per wave: 32 lanes/node, uint2 (4 bf16)/lane; 8-edge unroll.
// ---------------------------------------------------------------------------
__global__ __launch_bounds__(256, 8) void k_spmv_bf(const int* __restrict__ rowptr,
                                                    const int* __restrict__ col,
                                                    const float* __restrict__ dis,
                                                    const u16* __restrict__ Xs,
                                                    u16* __restrict__ SXb, int n) {
  const int tid = threadIdx.x;
  const int half = (tid >> 5) & 1;      // which node within the wave
  const int sub = tid & 31;             // lane within node (4 bf16 each)
  const int i = blockIdx.x * 8 + (tid >> 6) * 2 + half;
  if (i >= n) return;
  int j = rowptr[i];
  const int end = rowptr[i + 1];
  float a0 = 0.f, a1 = 0.f, a2 = 0.f, a3 = 0.f;

#define ROWQ(c) (*(const uint2*)(Xs + (size_t)(c) * 128 + sub * 4))
#define ACC(q)  do { uint2 _q = (q); \
                     a0 += bf2f(_q.x & 0xffffu); a1 += bf2f(_q.x >> 16); \
                     a2 += bf2f(_q.y & 0xffffu); a3 += bf2f(_q.y >> 16); } while (0)

  for (; (j & 3) && j < end; ++j) ACC(ROWQ(col[j]));
  for (; j + 7 < end; j += 8) {
    int4 c0 = *(const int4*)(col + j);
    int4 c1 = *(const int4*)(col + j + 4);
    uint2 q0 = ROWQ(c0.x), q1 = ROWQ(c0.y), q2 = ROWQ(c0.z), q3 = ROWQ(c0.w);
    uint2 q4 = ROWQ(c1.x), q5 = ROWQ(c1.y), q6 = ROWQ(c1.z), q7 = ROWQ(c1.w);
    ACC(q0); ACC(q1); ACC(q2); ACC(q3);
    ACC(q4); ACC(q5); ACC(q6); ACC(q7);
  }
  if (j + 3 < end) {
    int4 c0 = *(const int4*)(col + j);
    uint2 q0 = ROWQ(c0.x), q1 = ROWQ(c0.y), q2 = ROWQ(c0.z), q3 = ROWQ(c0.w);
    ACC(q0); ACC(q1); ACC(q2); ACC(q3);
    j += 4;
  }
  for (; j < end; ++j) ACC(ROWQ(col[j]));
#undef ROWQ
#undef ACC

  const float di = dis[i];
  uint2 o;
  o.x = (unsigned int)f2bf(a0 * di) | ((unsigned int)f2bf(a1 * di) << 16);
  o.y = (unsigned int)f2bf(a2 * di) | ((unsigned int)f2bf(a3 * di) << 16);
  *(uint2*)(SXb + (size_t)i * 128 + sub * 4) = o;
}

// ---------------------------------------------------------------------------
// MFMA fused layer, 4-way col-split with XCD-AWARE BLOCK SWIZZLE:
//   v = lrelu( A0@W0 + idis[row]*(A1s@W1) + bias )
// 1D grid of 32*ceil(gM/8) blocks. HW block b runs on XCD b&7 (dispatch
// round-robin); decode t=b>>3, cslice=t&3, rowblk=(b&7)+8*(t>>2) so the 4
// col-slices of one row-block are consecutive blocks ON THE SAME XCD ->
// its L2 fetches the 64KB A-panel once and serves all four.
// outs: bf16 dis[row]*v;  outf: fp32 v. NOT in-place safe.
// gfx950 16x16x32 mapping: A/B lane l -> row/col l&15, k (l>>4)*8+e;
//                          D lane l -> col l&15, row (l>>4)*4+e.
// ---------------------------------------------------------------------------
__global__ __launch_bounds__(256, 8) void k_mfma(const u16* __restrict__ A0,
                                                 const u16* __restrict__ A1s,
                                                 const u16* __restrict__ W0T,
                                                 const u16* __restrict__ W1T,
                                                 const float* __restrict__ bias,
                                                 const float* __restrict__ dis,
                                                 const float* __restrict__ idis,
                                                 u16* __restrict__ outs,
                                                 float* __restrict__ outf,
                                                 int M, int gM) {
  const int b = blockIdx.x;
  const int t = b >> 3;
  const int rowblk = (b & 7) + 8 * (t >> 2);
  if (rowblk >= gM) return;
  const int cslice = t & 3;

  const int lane = threadIdx.x & 63;
  const int wv = threadIdx.x >> 6;
  const int row0 = rowblk * 128 + wv * 32;
  const int c0off = cslice * 32;         // column slice
  const int r = lane & 15;
  const int kg = lane >> 4;

  f32x4 accA[2][2], accB[2][2];
#pragma unroll
  for (int a = 0; a < 2; ++a)
#pragma unroll
    for (int j = 0; j < 2; ++j) {
      accA[a][j] = (f32x4){0.f, 0.f, 0.f, 0.f};
      accB[a][j] = (f32x4){0.f, 0.f, 0.f, 0.f};
    }

  const int ra0 = min(row0 + r, M - 1);
  const int ra1 = min(row0 + 16 + r, M - 1);

  // A0 @ W0 -> accA
#pragma unroll
  for (int kk = 0; kk < 4; ++kk) {
    const int k0 = kk * 32 + kg * 8;
    bf16x8 a0 = *(const bf16x8*)(A0 + (size_t)ra0 * 128 + k0);
    bf16x8 a1 = *(const bf16x8*)(A0 + (size_t)ra1 * 128 + k0);
#pragma unroll
    for (int j = 0; j < 2; ++j) {
      bf16x8 b2 = *(const bf16x8*)(W0T + (size_t)(c0off + j * 16 + r) * 128 + k0);
      accA[0][j] = __builtin_amdgcn_mfma_f32_16x16x32_bf16(a0, b2, accA[0][j], 0, 0, 0);
      accA[1][j] = __builtin_amdgcn_mfma_f32_16x16x32_bf16(a1, b2, accA[1][j], 0, 0, 0);
    }
  }
  // A1s @ W1 -> accB
#pragma unroll
  for (int kk = 0; kk < 4; ++kk) {
    const int k0 = kk * 32 + kg * 8;
    bf16x8 a0 = *(const bf16x8*)(A1s + (size_t)ra0 * 128 + k0);
    bf16x8 a1 = *(const bf16x8*)(A1s + (size_t)ra1 * 128 + k0);
#pragma unroll
    for (int j = 0; j < 2; ++j) {
      bf16x8 b2 = *(const bf16x8*)(W1T + (size_t)(c0off + j * 16 + r) * 128 + k0);
      accB[0][j] = __builtin_amdgcn_mfma_f32_16x16x32_bf16(a0, b2, accB[0][j], 0, 0, 0);
      accB[1][j] = __builtin_amdgcn_mfma_f32_16x16x32_bf16(a1, b2, accB[1][j], 0, 0, 0);
    }
  }

#pragma unroll
  for (int rf = 0; rf < 2; ++rf)
#pragma unroll
    for (int e = 0; e < 4; ++e) {
      const int row = row0 + rf * 16 + kg * 4 + e;
      if (row >= M) continue;
      const float ids = idis[row];
      const float ds = dis[row];
#pragma unroll
      for (int j = 0; j < 2; ++j) {
        const int c = c0off + j * 16 + r;
        float v = accA[rf][j][e] + ids * accB[rf][j][e] + bias[c];
        v = (v > 0.f) ? v : 0.01f * v;
        if (outf) outf[(size_t)row * 128 + c] = v;
        if (outs) outs[(size_t)row * 128 + c] = f2bf(v * ds);
      }
    }
}

// ---------------------------------------------------------------------------
// FC head via MFMA, scaled input: y = idis[row]*(hs3@fcT) + fcb.
// hs3 bf16 [M,128] (dis-scaled h3), fcT bf16 [64][128]. hs3 may live in the
// y region (row-aligned): each wave reads its rows before storing them.
// ---------------------------------------------------------------------------
__global__ __launch_bounds__(256) void k_fc_mfma(const u16* __restrict__ hs3,
                                                 const u16* __restrict__ fcT,
                                                 const float* __restrict__ fcb,
                                                 const float* __restrict__ idis,
                                                 float* __restrict__ y, int M) {
  const int lane = threadIdx.x & 63;
  const int wv = threadIdx.x >> 6;
  const int row0 = blockIdx.x * 128 + wv * 32;
  const int r = lane & 15;
  const int kg = lane >> 4;

  f32x4 acc[2][4];
#pragma unroll
  for (int a = 0; a < 2; ++a)
#pragma unroll
    for (int j = 0; j < 4; ++j) acc[a][j] = (f32x4){0.f, 0.f, 0.f, 0.f};

  const int ra0 = min(row0 + r, M - 1);
  const int ra1 = min(row0 + 16 + r, M - 1);

#pragma unroll
  for (int kk = 0; kk < 4; ++kk) {
    const int k0 = kk * 32 + kg * 8;
    bf16x8 a0 = *(const bf16x8*)(hs3 + (size_t)ra0 * 128 + k0);
    bf16x8 a1 = *(const bf16x8*)(hs3 + (size_t)ra1 * 128 + k0);
#pragma unroll
    for (int j = 0; j < 4; ++j) {
      bf16x8 b = *(const bf16x8*)(fcT + (size_t)(j * 16 + r) * 128 + k0);
      acc[0][j] = __builtin_amdgcn_mfma_f32_16x16x32_bf16(a0, b, acc[0][j], 0, 0, 0);
      acc[1][j] = __builtin_amdgcn_mfma_f32_16x16x32_bf16(a1, b, acc[1][j], 0, 0, 0);
    }
  }

#pragma unroll
  for (int rf = 0; rf < 2; ++rf)
#pragma unroll
    for (int e = 0; e < 4; ++e) {
      const int row = row0 + rf * 16 + kg * 4 + e;
      if (row >= M) continue;
      const float ids = idis[row];
#pragma unroll
      for (int j = 0; j < 4; ++j) {
        const int c = j * 16 + r;
        y[(size_t)row * 64 + c] = ids * acc[rf][j][e] + fcb[c];
      }
    }
}

// ---------------------------------------------------------------------------

extern "C" void kernel_launch(void* const* d_in, const int* in_sizes, int n_in,
                              void* d_out, int out_size, void* d_ws, size_t ws_size,
                              hipStream_t stream) {
  const float* X  = (const float*)d_in[0];
  const int* ei   = (const int*)d_in[1];
  const float* gw1 = (const float*)d_in[3];
  const float* gb1 = (const float*)d_in[4];
  const float* lw1 = (const float*)d_in[5];
  const float* lb1 = (const float*)d_in[6];
  const float* gw2 = (const float*)d_in[7];
  const float* gb2 = (const float*)d_in[8];
  const float* lw2 = (const float*)d_in[9];
  const float* lb2 = (const float*)d_in[10];
  const float* gw3 = (const float*)d_in[11];
  const float* gb3 = (const float*)d_in[12];
  const float* lw3 = (const float*)d_in[13];
  const float* lb3 = (const float*)d_in[14];
  const float* fcw = (const float*)d_in[15];
  const float* fcb = (const float*)d_in[16];

  const int n = in_sizes[0] / 128;
  const int E = in_sizes[1] / 2;
  const int tot = E + n;
  const int B = (n + 255) >> 8;        // buckets (<=512)
  const int chunk = (E + G_CHUNKS - 1) / G_CHUNKS;

  char* ws = (char*)d_ws;
  size_t off = 0;
  auto alloc = [&](size_t bytes) -> void* {
    void* p = ws + off;
    off = (off + bytes + 255) & ~(size_t)255;
    return p;
  };
  int* ghist   = (int*)alloc((size_t)B * G_CHUNKS * 4);
  int* btot    = (int*)alloc(512 * 4);
  int* boff    = (int*)alloc((size_t)(B + 1) * 4);
  int* rowptr  = (int*)alloc((size_t)(n + 1) * 4);
  float* dis   = (float*)alloc((size_t)n * 4);
  float* idis  = (float*)alloc((size_t)n * 4);
  int* col     = (int*)alloc((size_t)tot * 4);
  unsigned int* ebuf = (unsigned int*)alloc((size_t)E * 4);
  u16* Xs      = (u16*)alloc((size_t)n * 128 * 2);   // scaled features ping A
  u16* SXb     = (u16*)alloc((size_t)n * 128 * 2);
  u16* WT      = (u16*)alloc((size_t)6 * 16384 * 2);
  u16* fcT     = (u16*)alloc((size_t)64 * 128 * 2);
  float* bias  = (float*)alloc(384 * 4);          // total ~66 MB

  float* outh = (float*)d_out;                 // [n,128] final h fp32
  float* outy = outh + (size_t)n * 128;        // [n,64]  final y fp32
  u16* hb = (u16*)outy;  // scaled-feature ping B in y-region (row-aligned);
                         // overwritten row-by-row by k_fc_mfma at the end.

  const int gM = (n + 127) / 128;
  const int gMswz = 32 * ((gM + 7) / 8);   // swizzled 1D grid (4 cslices x gM)
  const int gW = (n + 7) / 8;              // 8 nodes per block (2 per wave)
  const int g8 = (n * 128 / 8 + 255) / 256;

  // ---- CSR build (counting sort) ----
  k_hist<<<G_CHUNKS, 256, 0, stream>>>(ei, ghist, E, B, chunk);
  k_hscan<<<B, 256, 0, stream>>>(ghist, btot);
  k_bscan<<<1, 512, 0, stream>>>(btot, boff, B, rowptr, n, E, tot);
  k_scatter<<<G_CHUNKS, 256, 0, stream>>>(ei, ghist, boff, ebuf, E, B, chunk);
  k_cfill<<<B, 256, 0, stream>>>(ebuf, boff, rowptr, col, dis, idis, n);

  // ---- dtype prep (k_cvt needs dis -> after cfill) ----
  k_cvt<<<g8, 256, 0, stream>>>(X, dis, Xs, n * 128 / 8);
  k_prep<<<835, 128, 0, stream>>>(gw1, lw1, gw2, lw2, gw3, lw3,
                                  gb1, lb1, gb2, lb2, gb3, lb3, fcw,
                                  WT, bias, fcT);

  // ---- layer 1: gather Xs; A1s=Xs -> hs1:hb ----
  k_spmv_bf<<<gW, 256, 0, stream>>>(rowptr, col, dis, Xs, SXb, n);
  k_mfma<<<gMswz, 256, 0, stream>>>(SXb, Xs, WT, WT + 16384, bias,
                                    dis, idis, hb, nullptr, n, gM);
  // ---- layer 2: gather hs1; A1s=hb -> hs2:Xs ----
  k_spmv_bf<<<gW, 256, 0, stream>>>(rowptr, col, dis, hb, SXb, n);
  k_mfma<<<gMswz, 256, 0, stream>>>(SXb, hb, WT + 2 * 16384, WT + 3 * 16384,
                                    bias + 128, dis, idis, Xs, nullptr, n, gM);
  // ---- layer 3: gather hs2; A1s=Xs -> h3 fp32:outh, hs3:hb ----
  k_spmv_bf<<<gW, 256, 0, stream>>>(rowptr, col, dis, Xs, SXb, n);
  k_mfma<<<gMswz, 256, 0, stream>>>(SXb, Xs, WT + 4 * 16384, WT + 5 * 16384,
                                    bias + 256, dis, idis, hb, outh, n, gM);
  // ---- FC head (reads hs3 in hb, y = idis*(hs3@fcT)+fcb, overwrites hb) ----
  k_fc_mfma<<<gM, 256, 0, stream>>>(hb, fcT, fcb, idis, outy, n);
}